// Round 1
// baseline (90017.657 us; speedup 1.0000x reference)
//
#include <hip/hip_runtime.h>

#define N_ 8
#define S_ 2048
#define E_ 512
#define H_ 8
#define D_ 64
#define P_ 16
#define KL_ (S_ + P_)   // 2064
#define SCALE 0.04419417382415922f  // 1/sqrt(512)

// ---------------- QKV projections ----------------
// grid: N*S/16 blocks, 256 threads. out[e'] = sum_d x[h*64+d] * W[e'][d]
__global__ __launch_bounds__(256) void proj_kernel(
    const float* __restrict__ values,
    const float* __restrict__ keys,
    const float* __restrict__ queries,
    const float* __restrict__ Wv,
    const float* __restrict__ Wk,
    const float* __restrict__ Wq,
    float* __restrict__ Vp, float* __restrict__ Kp, float* __restrict__ Qp)
{
    __shared__ float Ws[3][64][65];   // pad 65: conflict-free row reads
    __shared__ float xs[3][512];
    const int t = threadIdx.x;
    for (int idx = t; idx < 3*4096; idx += 256) {
        int tensor = idx >> 12, rem = idx & 4095;
        int row = rem >> 6, col = rem & 63;
        const float* W = (tensor==0) ? Wv : (tensor==1) ? Wk : Wq;
        Ws[tensor][row][col] = W[rem];
    }
    __syncthreads();
    const int rbase = blockIdx.x * 16;
    for (int r = 0; r < 16; ++r) {
        const int row = rbase + r;
        const int n = row >> 11, s = row & 2047;
        const size_t off = (size_t)row * 512;
        for (int idx = t; idx < 3*128; idx += 256) {
            int tensor = idx >> 7, c4 = idx & 127;
            const float* src = (tensor==0) ? values : (tensor==1) ? keys : queries;
            *(float4*)&xs[tensor][c4*4] = *(const float4*)&src[off + c4*4];
        }
        __syncthreads();
        for (int jj = t; jj < 1536; jj += 256) {
            int tensor = jj >> 9, e = jj & 511;
            int h = e >> 6, dout = e & 63;
            float acc = 0.f;
            const float* x = &xs[tensor][h*64];
            const float* w = &Ws[tensor][dout][0];
            #pragma unroll
            for (int d = 0; d < 64; ++d) acc += x[d]*w[d];
            if (tensor == 0)      Vp[(size_t)(n*KL_+s)*512 + e] = acc;
            else if (tensor == 1) Kp[(size_t)(n*KL_+s)*512 + e] = acc;
            else                  Qp[off + e] = acc;
        }
        __syncthreads();
    }
}

// ---------------- persistent token append (raw pk/pv, unprojected) ----------------
__global__ __launch_bounds__(256) void persist_kernel(
    const float* __restrict__ pk, const float* __restrict__ pv,
    float* __restrict__ Kp, float* __restrict__ Vp)
{
    int id = blockIdx.x*256 + threadIdx.x;   // 0..131071
    int tensor = id >> 16;
    int rem = id & 65535;
    int n = rem >> 13;          // P*H*D = 8192
    int rem2 = rem & 8191;
    int p = rem2 >> 9;
    int e = rem2 & 511;
    size_t dst = (size_t)(n*KL_ + S_ + p)*512 + e;
    if (tensor == 0) Kp[dst] = pk[p*512 + e];
    else             Vp[dst] = pv[p*512 + e];
}

// ---------------- fused two-pass attention ----------------
// grid (S/16, N), 256 threads. thread t -> (qi=t>>4, li=t&15) pair.
__global__ __launch_bounds__(256) void attn_kernel(
    const float* __restrict__ Qp, const float* __restrict__ Kp,
    const float* __restrict__ Vp, const int* __restrict__ mask,
    const float* __restrict__ pre_th, const float* __restrict__ post_th,
    float* __restrict__ Oh)
{
    __shared__ float qs[16][516];
    __shared__ float ks[16][516];
    __shared__ float vs[16][516];
    __shared__ float ps[16][16][9];
    __shared__ float pre_s[64], post_s[64];

    const int t = threadIdx.x;
    const int n = blockIdx.y;
    const int q0 = blockIdx.x * 16;
    const int qi = t >> 4, li = t & 15;

    if (t < 64) pre_s[t] = pre_th[t];
    else if (t < 128) post_s[t-64] = post_th[t-64];

    float slope[8];
    #pragma unroll
    for (int j = 0; j < 8; ++j) slope[j] = exp2f(-(float)(j+1));

    for (int idx = t; idx < 16*128; idx += 256) {
        int row = idx >> 7, c4 = idx & 127;
        *(float4*)&qs[row][c4*4] =
            *(const float4*)&Qp[(size_t)(n*S_ + q0 + row)*512 + c4*4];
    }

    float m[8], Z[8];
    #pragma unroll
    for (int j = 0; j < 8; ++j) { m[j] = -3e38f; Z[j] = 0.f; }

    const float qpos = (float)(q0 + qi);

    // ---- pass 1: online (m, Z) per (row, head) ----
    for (int tile = 0; tile < 129; ++tile) {
        __syncthreads();
        for (int idx = t; idx < 16*128; idx += 256) {
            int row = idx >> 7, c4 = idx & 127;
            *(float4*)&ks[row][c4*4] =
                *(const float4*)&Kp[(size_t)(n*KL_ + tile*16 + row)*512 + c4*4];
        }
        __syncthreads();
        float e[8];
        #pragma unroll
        for (int j = 0; j < 8; ++j) {
            float acc = 0.f;
            #pragma unroll
            for (int d4 = 0; d4 < 16; ++d4) {
                float4 qa = *(const float4*)&qs[qi][j*64 + d4*4];
                float4 kb = *(const float4*)&ks[li][j*64 + d4*4];
                acc += qa.x*kb.x + qa.y*kb.y + qa.z*kb.z + qa.w*kb.w;
            }
            e[j] = acc;
        }
        int mv = 1;
        if (tile < 128) {
            float dist = fabsf(qpos - (float)(tile*16 + li));
            #pragma unroll
            for (int j = 0; j < 8; ++j) e[j] -= dist * slope[j];
            mv = mask[(size_t)(n*S_ + q0 + qi)*S_ + tile*16 + li];
        }
        #pragma unroll
        for (int i = 0; i < 8; ++i) {
            float acc = 0.f;
            #pragma unroll
            for (int j = 0; j < 8; ++j) acc += pre_s[i*8+j]*e[j];
            float lg = ((mv == 0) ? -1e4f : acc) * SCALE;
            float tm = lg;
            tm = fmaxf(tm, __shfl_xor(tm, 1, 16));
            tm = fmaxf(tm, __shfl_xor(tm, 2, 16));
            tm = fmaxf(tm, __shfl_xor(tm, 4, 16));
            tm = fmaxf(tm, __shfl_xor(tm, 8, 16));
            float ts = __expf(lg - tm);
            ts += __shfl_xor(ts, 1, 16);
            ts += __shfl_xor(ts, 2, 16);
            ts += __shfl_xor(ts, 4, 16);
            ts += __shfl_xor(ts, 8, 16);
            float nm = fmaxf(m[i], tm);
            Z[i] = Z[i]*__expf(m[i]-nm) + ts*__expf(tm-nm);
            m[i] = nm;
        }
    }
    float invZ[8];
    #pragma unroll
    for (int i = 0; i < 8; ++i) invZ[i] = 1.f / Z[i];

    // ---- pass 2: recompute, normalize, post_th mix, PV ----
    const int ihead = li >> 1;     // PV: thread covers e in [li*32, li*32+32)
    float acc[32];
    #pragma unroll
    for (int d = 0; d < 32; ++d) acc[d] = 0.f;

    for (int tile = 0; tile < 129; ++tile) {
        __syncthreads();
        for (int idx = t; idx < 16*128; idx += 256) {
            int row = idx >> 7, c4 = idx & 127;
            size_t goff = (size_t)(n*KL_ + tile*16 + row)*512 + c4*4;
            *(float4*)&ks[row][c4*4] = *(const float4*)&Kp[goff];
            *(float4*)&vs[row][c4*4] = *(const float4*)&Vp[goff];
        }
        __syncthreads();
        float e[8];
        #pragma unroll
        for (int j = 0; j < 8; ++j) {
            float acc2 = 0.f;
            #pragma unroll
            for (int d4 = 0; d4 < 16; ++d4) {
                float4 qa = *(const float4*)&qs[qi][j*64 + d4*4];
                float4 kb = *(const float4*)&ks[li][j*64 + d4*4];
                acc2 += qa.x*kb.x + qa.y*kb.y + qa.z*kb.z + qa.w*kb.w;
            }
            e[j] = acc2;
        }
        int mv = 1;
        if (tile < 128) {
            float dist = fabsf(qpos - (float)(tile*16 + li));
            #pragma unroll
            for (int j = 0; j < 8; ++j) e[j] -= dist*slope[j];
            mv = mask[(size_t)(n*S_ + q0 + qi)*S_ + tile*16 + li];
        }
        float p[8];
        #pragma unroll
        for (int i = 0; i < 8; ++i) {
            float accm = 0.f;
            #pragma unroll
            for (int j = 0; j < 8; ++j) accm += pre_s[i*8+j]*e[j];
            float fi = ((mv == 0) ? -1e4f : accm) * SCALE;
            p[i] = __expf(fi - m[i]) * invZ[i];
        }
        #pragma unroll
        for (int o = 0; o < 8; ++o) {
            float accp = 0.f;
            #pragma unroll
            for (int j = 0; j < 8; ++j) accp += post_s[o*8+j]*p[j];
            ps[qi][li][o] = accp;
        }
        __syncthreads();
        #pragma unroll
        for (int lt = 0; lt < 16; ++lt) {
            float pm = ps[qi][lt][ihead];
            #pragma unroll
            for (int k4 = 0; k4 < 8; ++k4) {
                int idx = (k4 + li) & 7;                 // stagger: spread banks
                float4 vv = *(const float4*)&vs[lt][li*32 + idx*4];
                acc[idx*4+0] += pm*vv.x;
                acc[idx*4+1] += pm*vv.y;
                acc[idx*4+2] += pm*vv.z;
                acc[idx*4+3] += pm*vv.w;
            }
        }
    }
    size_t obase = (size_t)(n*S_ + q0 + qi)*512 + li*32;
    #pragma unroll
    for (int k4 = 0; k4 < 8; ++k4) {
        float4 v4 = make_float4(acc[k4*4], acc[k4*4+1], acc[k4*4+2], acc[k4*4+3]);
        *(float4*)&Oh[obase + k4*4] = v4;
    }
}

// ---------------- output projection: out = Oh @ Wo^T + bo ----------------
// grid (512/64, 16384/64), 256 threads, 64x64 tile, 4x4 micro-tile
__global__ __launch_bounds__(256) void out_proj_kernel(
    const float* __restrict__ Oh, const float* __restrict__ Wo,
    const float* __restrict__ bo, float* __restrict__ out)
{
    __shared__ float As[64][33];
    __shared__ float Bs[64][33];
    const int t = threadIdx.x;
    const int tx = t & 15, ty = t >> 4;
    const int r0 = blockIdx.y * 64;
    const int c0 = blockIdx.x * 64;
    float acc[4][4] = {};
    for (int k0 = 0; k0 < 512; k0 += 32) {
        __syncthreads();
        for (int idx = t; idx < 2048; idx += 256) {
            int row = idx >> 5, col = idx & 31;
            As[row][col] = Oh[(size_t)(r0+row)*512 + k0 + col];
            Bs[row][col] = Wo[(size_t)(c0+row)*512 + k0 + col];
        }
        __syncthreads();
        for (int kk = 0; kk < 32; ++kk) {
            float a[4], b[4];
            #pragma unroll
            for (int i = 0; i < 4; ++i) a[i] = As[ty*4+i][kk];
            #pragma unroll
            for (int j = 0; j < 4; ++j) b[j] = Bs[tx*4+j][kk];
            #pragma unroll
            for (int i = 0; i < 4; ++i)
                #pragma unroll
                for (int j = 0; j < 4; ++j)
                    acc[i][j] += a[i]*b[j];
        }
    }
    #pragma unroll
    for (int i = 0; i < 4; ++i) {
        float4 v4 = make_float4(acc[i][0] + bo[c0+tx*4+0],
                                acc[i][1] + bo[c0+tx*4+1],
                                acc[i][2] + bo[c0+tx*4+2],
                                acc[i][3] + bo[c0+tx*4+3]);
        *(float4*)&out[(size_t)(r0+ty*4+i)*512 + c0 + tx*4] = v4;
    }
}

extern "C" void kernel_launch(void* const* d_in, const int* in_sizes, int n_in,
                              void* d_out, int out_size, void* d_ws, size_t ws_size,
                              hipStream_t stream)
{
    const float* values  = (const float*)d_in[0];
    const float* keys    = (const float*)d_in[1];
    const float* queries = (const float*)d_in[2];
    const int*   mask    = (const int*)d_in[3];
    const float* Wv      = (const float*)d_in[4];
    const float* Wk      = (const float*)d_in[5];
    const float* Wq      = (const float*)d_in[6];
    const float* Wo      = (const float*)d_in[7];
    const float* bo      = (const float*)d_in[8];
    const float* pre_th  = (const float*)d_in[9];
    const float* post_th = (const float*)d_in[10];
    const float* pk      = (const float*)d_in[11];
    const float* pv      = (const float*)d_in[12];

    float* ws = (float*)d_ws;
    float* Qp = ws;                               // N*S*E
    float* Kp = Qp + (size_t)N_*S_*E_;            // N*KL*E
    float* Vp = Kp + (size_t)N_*KL_*E_;           // N*KL*E
    float* Oh = Vp + (size_t)N_*KL_*E_;           // N*S*E

    hipLaunchKernelGGL(proj_kernel, dim3(N_*S_/16), dim3(256), 0, stream,
                       values, keys, queries, Wv, Wk, Wq, Vp, Kp, Qp);
    hipLaunchKernelGGL(persist_kernel, dim3(512), dim3(256), 0, stream,
                       pk, pv, Kp, Vp);
    hipLaunchKernelGGL(attn_kernel, dim3(S_/16, N_), dim3(256), 0, stream,
                       Qp, Kp, Vp, mask, pre_th, post_th, Oh);
    hipLaunchKernelGGL(out_proj_kernel, dim3(8, 256), dim3(256), 0, stream,
                       Oh, Wo, bo, (float*)d_out);
}

// Round 2
// 975.177 us; speedup vs baseline: 92.3091x; 92.3091x over previous
//
#include <hip/hip_runtime.h>

#define N_ 8
#define S_ 2048
#define E_ 512
#define KL_ 2064          // S + P
#define NT_ 129           // k-tiles of 16
#define SCALE 0.04419417382415922f
#define MASKVAL (-1e4f * SCALE)

typedef unsigned short u16;
typedef unsigned int u32;
typedef __attribute__((ext_vector_type(2))) float f32x2;
typedef __attribute__((ext_vector_type(4))) float f32x4;
typedef __attribute__((ext_vector_type(4))) short bf16x4;
typedef __attribute__((ext_vector_type(8))) short bf16x8;

__device__ __forceinline__ u16 f2bf(float x) {
  u32 u = __float_as_uint(x);
  u32 r = (u + 0x7FFFu + ((u >> 16) & 1u)) >> 16;
  return (u16)r;
}

__device__ __forceinline__ f32x4 mfma16(bf16x4 a, bf16x4 b, f32x4 c) {
#if __has_builtin(__builtin_amdgcn_mfma_f32_16x16x16bf16_1k)
  return __builtin_amdgcn_mfma_f32_16x16x16bf16_1k(a, b, c, 0, 0, 0);
#elif __has_builtin(__builtin_amdgcn_mfma_f32_16x16x16_bf16)
  return __builtin_amdgcn_mfma_f32_16x16x16_bf16(a, b, c, 0, 0, 0);
#else
  f32x4 d;
  asm("v_mfma_f32_16x16x16_bf16 %0, %1, %2, %3" : "=v"(d) : "v"(a), "v"(b), "v"(c));
  return d;
#endif
}

// ---------------- mask pack: 1 bit per (q,l), layout bm[n][w=64][q=2048] ----------------
__global__ __launch_bounds__(256) void maskpack_kernel(const int* __restrict__ mask,
                                                       u32* __restrict__ bm) {
  const int t = threadIdx.x;
  const int w = t >> 6, lane = t & 63;
  const int blk = blockIdx.x;           // 4096 blocks: (n, 4 q-rows)
  const int n = blk >> 9;
  const int qrow = ((blk & 511) << 2) + w;
  const int* row = mask + ((size_t)n * S_ + qrow) * S_;
  __shared__ u32 tl[4][64];
  u32 myword = 0;
  #pragma unroll 4
  for (int k = 0; k < 32; ++k) {
    int v = row[k * 64 + lane];
    unsigned long long b = __ballot(v != 0);
    if ((lane >> 1) == k) myword = (lane & 1) ? (u32)(b >> 32) : (u32)b;
  }
  tl[w][lane] = myword;
  __syncthreads();
  const int qq = t & 3, wi = t >> 2;
  const int qb = ((blk & 511) << 2) + qq;
  bm[((size_t)n * 64 + wi) * S_ + qb] = tl[qq][wi];
}

// ---------------- projections (MFMA): Qp/Kp bf16 natural, V written transposed VT[n][e][l] ----------------
__global__ __launch_bounds__(256, 2) void proj_kernel(
    const float* __restrict__ V_, const float* __restrict__ K_, const float* __restrict__ Q_,
    const float* __restrict__ Wv, const float* __restrict__ Wk, const float* __restrict__ Wq,
    u16* __restrict__ Kp, u16* __restrict__ Qp, u16* __restrict__ VT) {
  __shared__ u16 xt[64 * 512];
  __shared__ u16 wt[64 * 64];
  const int tz = blockIdx.y;            // 0=V 1=K 2=Q
  const float* X = (tz == 0) ? V_ : (tz == 1) ? K_ : Q_;
  const float* W = (tz == 0) ? Wv : (tz == 1) ? Wk : Wq;
  const int t = threadIdx.x, lane = t & 63, w = t >> 6, g = lane >> 4, li = lane & 15;
  const int rb = blockIdx.x * 64;       // flat row base (n*2048+s)
  const int nn = rb >> 11, sb = rb & 2047;

  // stage W (64x64 f32 -> bf16, slot-swizzled rows of 8 slots)
  for (int c = t; c < 512; c += 256) {
    int r = c >> 3, s = c & 7;
    float4 a = *(const float4*)&W[r * 64 + s * 8];
    float4 b = *(const float4*)&W[r * 64 + s * 8 + 4];
    bf16x8 v = {(short)f2bf(a.x), (short)f2bf(a.y), (short)f2bf(a.z), (short)f2bf(a.w),
                (short)f2bf(b.x), (short)f2bf(b.y), (short)f2bf(b.z), (short)f2bf(b.w)};
    *(bf16x8*)&wt[r * 64 + ((s ^ (r & 7)) * 8)] = v;
  }
  // stage X tile (64 rows x 512, 64 slots/row, swizzled)
  for (int c = t; c < 4096; c += 256) {
    int r = c >> 6, s = c & 63;
    const float* src = &X[(size_t)(rb + r) * 512 + s * 8];
    float4 a = *(const float4*)src;
    float4 b = *(const float4*)(src + 4);
    bf16x8 v = {(short)f2bf(a.x), (short)f2bf(a.y), (short)f2bf(a.z), (short)f2bf(a.w),
                (short)f2bf(b.x), (short)f2bf(b.y), (short)f2bf(b.z), (short)f2bf(b.w)};
    *(bf16x8*)&xt[r * 512 + ((s ^ (r & 7)) * 8)] = v;
  }
  __syncthreads();

  bf16x8 fx[8][2];
  #pragma unroll
  for (int h = 0; h < 8; ++h)
    #pragma unroll
    for (int dh = 0; dh < 2; ++dh) {
      int row = w * 16 + li;
      fx[h][dh] = *(const bf16x8*)&xt[row * 512 + (((h * 8 + dh * 4 + g) ^ (row & 7)) * 8)];
    }
  bf16x8 fw[4][2];
  #pragma unroll
  for (int c = 0; c < 4; ++c)
    #pragma unroll
    for (int dh = 0; dh < 2; ++dh) {
      int row = c * 16 + li;
      fw[c][dh] = *(const bf16x8*)&wt[row * 64 + (((dh * 4 + g) ^ (row & 7)) * 8)];
    }

  f32x4 C[8][4];
  #pragma unroll
  for (int h = 0; h < 8; ++h)
    #pragma unroll
    for (int c = 0; c < 4; ++c) C[h][c] = (f32x4){0.f, 0.f, 0.f, 0.f};

  if (tz == 0) {  // V^T mode: C[h][ec] = W(e' rows) x X^T(l cols)
    #pragma unroll
    for (int h = 0; h < 8; ++h)
      #pragma unroll
      for (int dh = 0; dh < 2; ++dh)
        #pragma unroll
        for (int c = 0; c < 4; ++c)
          C[h][c] = __builtin_amdgcn_mfma_f32_16x16x32_bf16(fw[c][dh], fx[h][dh], C[h][c], 0, 0, 0);
    #pragma unroll
    for (int h = 0; h < 8; ++h)
      #pragma unroll
      for (int c = 0; c < 4; ++c)
        #pragma unroll
        for (int r = 0; r < 4; ++r) {
          int e = h * 64 + c * 16 + g * 4 + r;
          VT[((size_t)(nn * 512 + e)) * KL_ + sb + w * 16 + li] = f2bf(C[h][c][r]);
        }
  } else {        // Q/K mode: C[h][nc] = X(s rows) x W^T(e cols)
    #pragma unroll
    for (int h = 0; h < 8; ++h)
      #pragma unroll
      for (int dh = 0; dh < 2; ++dh)
        #pragma unroll
        for (int c = 0; c < 4; ++c)
          C[h][c] = __builtin_amdgcn_mfma_f32_16x16x32_bf16(fx[h][dh], fw[c][dh], C[h][c], 0, 0, 0);
    #pragma unroll
    for (int h = 0; h < 8; ++h)
      #pragma unroll
      for (int c = 0; c < 4; ++c)
        #pragma unroll
        for (int r = 0; r < 4; ++r) {
          int e = h * 64 + c * 16 + li;
          u16 val = f2bf(C[h][c][r]);
          if (tz == 2) Qp[(size_t)(rb + w * 16 + g * 4 + r) * 512 + e] = val;
          else Kp[((size_t)nn * KL_ + sb + w * 16 + g * 4 + r) * 512 + e] = val;
        }
  }
}

// ---------------- persistent tokens (raw, bf16) ----------------
__global__ __launch_bounds__(256) void persist_kernel(const float* __restrict__ pk,
                                                      const float* __restrict__ pv,
                                                      u16* __restrict__ Kp, u16* __restrict__ VT) {
  int id = blockIdx.x * 256 + threadIdx.x;   // 2*8*16*512
  int tensor = id >> 16, rem = id & 65535;
  int n = rem >> 13, p = (rem >> 9) & 15, e = rem & 511;
  if (tensor == 0) Kp[((size_t)n * KL_ + S_ + p) * 512 + e] = f2bf(pk[p * 512 + e]);
  else VT[((size_t)(n * 512 + e)) * KL_ + S_ + p] = f2bf(pv[p * 512 + e]);
}

// ---------------- fused attention: 2-pass, MFMA, talking heads, ALiBi ----------------
__global__ __launch_bounds__(256, 1) void attn_kernel(
    const u16* __restrict__ Qp, const u16* __restrict__ Kp, const u16* __restrict__ VT,
    const u32* __restrict__ bm, const float* __restrict__ pre_th,
    const float* __restrict__ post_th, float* __restrict__ Oh) {
  __shared__ u16 Kt[2][16 * 512];
  __shared__ u16 Vt[2][512 * 16];
  __shared__ u32 mlds[64 * 64];

  const int t = threadIdx.x, lane = t & 63, w = t >> 6, g = lane >> 4, li = lane & 15;
  const int n = blockIdx.y, q0 = blockIdx.x * 64;
  const int myq = q0 + w * 16 + li;

  // mask words for this block's 64 q
  {
    const u32* src = bm + (size_t)n * 64 * S_;
    for (int r = 0; r < 16; ++r) {
      int wr = w * 16 + r;
      mlds[wr * 64 + lane] = src[(size_t)wr * S_ + q0 + lane];
    }
  }
  // Q fragments (held in regs for the whole kernel)
  bf16x8 qf[8][2];
  {
    const u16* qrow = Qp + (size_t)(n * S_ + myq) * 512;
    #pragma unroll
    for (int h = 0; h < 8; ++h)
      #pragma unroll
      for (int dh = 0; dh < 2; ++dh)
        qf[h][dh] = *(const bf16x8*)(qrow + h * 64 + dh * 32 + g * 8);
  }
  // mixed ALiBi slopes (scaled): msl[i] = SCALE * sum_j pre[i][j] * 2^-(j+1)
  float msl[8];
  #pragma unroll
  for (int i = 0; i < 8; ++i) {
    float a = 0.f;
    #pragma unroll
    for (int j = 0; j < 8; ++j) a += pre_th[i * 8 + j] * exp2f(-(float)(j + 1));
    msl[i] = a * SCALE;
  }

  float m1[8], Zr[8];
  #pragma unroll
  for (int i = 0; i < 8; ++i) { m1[i] = -1e30f; Zr[i] = 0.f; }

  const u16* Kbase = Kp + (size_t)n * KL_ * 512;
  const u16* Vbase = VT + (size_t)n * 512 * KL_;
  bf16x8 kreg[4], vreg[4];

  // ================= PASS 1 =================
  #pragma unroll
  for (int rr = 0; rr < 4; ++rr) {
    int row = w * 4 + rr;
    kreg[rr] = *(const bf16x8*)(Kbase + (size_t)row * 512 + lane * 8);
  }
  #pragma unroll
  for (int rr = 0; rr < 4; ++rr) {
    int row = w * 4 + rr;
    *(bf16x8*)&Kt[0][row * 512 + (lane ^ (row & 7)) * 8] = kreg[rr];
  }
  for (int tt = 0; tt < NT_; ++tt) {
    __syncthreads();
    if (tt + 1 < NT_) {
      #pragma unroll
      for (int rr = 0; rr < 4; ++rr) {
        int row = w * 4 + rr;
        kreg[rr] = *(const bf16x8*)(Kbase + (size_t)((tt + 1) * 16 + row) * 512 + lane * 8);
      }
    }
    const u16* kb = &Kt[tt & 1][0];
    f32x4 C[8];
    #pragma unroll
    for (int h = 0; h < 8; ++h) C[h] = (f32x4){0.f, 0.f, 0.f, 0.f};
    #pragma unroll
    for (int h = 0; h < 8; ++h)
      #pragma unroll
      for (int dh = 0; dh < 2; ++dh) {
        bf16x8 a = *(const bf16x8*)(kb + li * 512 + (((h * 8 + dh * 4 + g) ^ (li & 7)) * 8));
        C[h] = __builtin_amdgcn_mfma_f32_16x16x32_bf16(a, qf[h][dh], C[h], 0, 0, 0);
      }
    const u32 word = (tt < 128) ? mlds[(tt >> 1) * 64 + (w * 16 + li)] : 0xFFFFFFFFu;
    const u32 mbits = (word >> ((tt & 1) * 16 + g * 4)) & 0xFu;
    const bool doalibi = tt < 128;
    float dist[4];
    #pragma unroll
    for (int r = 0; r < 4; ++r) dist[r] = fabsf((float)(myq - (tt * 16 + g * 4 + r)));
    // pre-talking-heads mix
    f32x2 accl[8], acch[8];
    #pragma unroll
    for (int i = 0; i < 8; ++i) { accl[i] = (f32x2){0.f, 0.f}; acch[i] = (f32x2){0.f, 0.f}; }
    #pragma unroll
    for (int j = 0; j < 8; ++j) {
      f32x2 elo = {C[j].x, C[j].y}, ehi = {C[j].z, C[j].w};
      #pragma unroll
      for (int i = 0; i < 8; ++i) {
        float p = pre_th[i * 8 + j];
        accl[i] += p * elo; acch[i] += p * ehi;
      }
    }
    #pragma unroll
    for (int i = 0; i < 8; ++i) {
      float lg[4] = {accl[i].x * SCALE, accl[i].y * SCALE, acch[i].x * SCALE, acch[i].y * SCALE};
      if (doalibi) {
        #pragma unroll
        for (int r = 0; r < 4; ++r) lg[r] -= dist[r] * msl[i];
      }
      #pragma unroll
      for (int r = 0; r < 4; ++r) if (!((mbits >> r) & 1u)) lg[r] = MASKVAL;
      float tm = fmaxf(fmaxf(lg[0], lg[1]), fmaxf(lg[2], lg[3]));
      float nm = fmaxf(m1[i], tm);
      float s = __expf(lg[0] - nm) + __expf(lg[1] - nm) + __expf(lg[2] - nm) + __expf(lg[3] - nm);
      Zr[i] = Zr[i] * __expf(m1[i] - nm) + s;
      m1[i] = nm;
    }
    if (tt + 1 < NT_) {
      #pragma unroll
      for (int rr = 0; rr < 4; ++rr) {
        int row = w * 4 + rr;
        *(bf16x8*)&Kt[(tt + 1) & 1][row * 512 + (lane ^ (row & 7)) * 8] = kreg[rr];
      }
    }
  }
  // combine partials across lane groups (same q lives in lanes q, q+16, q+32, q+48)
  #pragma unroll
  for (int i = 0; i < 8; ++i) {
    #pragma unroll
    for (int off = 16; off <= 32; off <<= 1) {
      float mo = __shfl_xor(m1[i], off);
      float zo = __shfl_xor(Zr[i], off);
      float nm = fmaxf(m1[i], mo);
      Zr[i] = Zr[i] * __expf(m1[i] - nm) + zo * __expf(mo - nm);
      m1[i] = nm;
    }
    m1[i] += __logf(Zr[i]);   // fold 1/Z into the max
  }
  __syncthreads();

  // ================= PASS 2 =================
  f32x4 O[8][4];
  #pragma unroll
  for (int o = 0; o < 8; ++o)
    #pragma unroll
    for (int dc = 0; dc < 4; ++dc) O[o][dc] = (f32x4){0.f, 0.f, 0.f, 0.f};

  #pragma unroll
  for (int rr = 0; rr < 4; ++rr) {
    int row = w * 4 + rr;
    kreg[rr] = *(const bf16x8*)(Kbase + (size_t)row * 512 + lane * 8);
    int e = (w * 4 + rr) * 32 + (lane >> 1);
    vreg[rr] = *(const bf16x8*)(Vbase + (size_t)e * KL_ + (lane & 1) * 8);
  }
  #pragma unroll
  for (int rr = 0; rr < 4; ++rr) {
    int row = w * 4 + rr;
    *(bf16x8*)&Kt[0][row * 512 + (lane ^ (row & 7)) * 8] = kreg[rr];
    int e = (w * 4 + rr) * 32 + (lane >> 1);
    *(bf16x8*)&Vt[0][e * 16 + (lane & 1) * 8] = vreg[rr];
  }
  for (int tt = 0; tt < NT_; ++tt) {
    __syncthreads();
    if (tt + 1 < NT_) {
      #pragma unroll
      for (int rr = 0; rr < 4; ++rr) {
        int row = w * 4 + rr;
        kreg[rr] = *(const bf16x8*)(Kbase + (size_t)((tt + 1) * 16 + row) * 512 + lane * 8);
        int e = (w * 4 + rr) * 32 + (lane >> 1);
        vreg[rr] = *(const bf16x8*)(Vbase + (size_t)e * KL_ + (tt + 1) * 16 + (lane & 1) * 8);
      }
    }
    const u16* kb = &Kt[tt & 1][0];
    const u16* vb = &Vt[tt & 1][0];
    f32x4 C[8];
    #pragma unroll
    for (int h = 0; h < 8; ++h) C[h] = (f32x4){0.f, 0.f, 0.f, 0.f};
    #pragma unroll
    for (int h = 0; h < 8; ++h)
      #pragma unroll
      for (int dh = 0; dh < 2; ++dh) {
        bf16x8 a = *(const bf16x8*)(kb + li * 512 + (((h * 8 + dh * 4 + g) ^ (li & 7)) * 8));
        C[h] = __builtin_amdgcn_mfma_f32_16x16x32_bf16(a, qf[h][dh], C[h], 0, 0, 0);
      }
    const u32 word = (tt < 128) ? mlds[(tt >> 1) * 64 + (w * 16 + li)] : 0xFFFFFFFFu;
    const u32 mbits = (word >> ((tt & 1) * 16 + g * 4)) & 0xFu;
    const bool doalibi = tt < 128;
    float dist[4];
    #pragma unroll
    for (int r = 0; r < 4; ++r) dist[r] = fabsf((float)(myq - (tt * 16 + g * 4 + r)));
    f32x2 accl[8], acch[8];
    #pragma unroll
    for (int i = 0; i < 8; ++i) { accl[i] = (f32x2){0.f, 0.f}; acch[i] = (f32x2){0.f, 0.f}; }
    #pragma unroll
    for (int j = 0; j < 8; ++j) {
      f32x2 elo = {C[j].x, C[j].y}, ehi = {C[j].z, C[j].w};
      #pragma unroll
      for (int i = 0; i < 8; ++i) {
        float p = pre_th[i * 8 + j];
        accl[i] += p * elo; acch[i] += p * ehi;
      }
    }
    f32x2 ppl[8], pph[8];
    #pragma unroll
    for (int i = 0; i < 8; ++i) {
      float lg[4] = {accl[i].x * SCALE, accl[i].y * SCALE, acch[i].x * SCALE, acch[i].y * SCALE};
      if (doalibi) {
        #pragma unroll
        for (int r = 0; r < 4; ++r) lg[r] -= dist[r] * msl[i];
      }
      #pragma unroll
      for (int r = 0; r < 4; ++r) if (!((mbits >> r) & 1u)) lg[r] = MASKVAL;
      ppl[i] = (f32x2){__expf(lg[0] - m1[i]), __expf(lg[1] - m1[i])};
      pph[i] = (f32x2){__expf(lg[2] - m1[i]), __expf(lg[3] - m1[i])};
    }
    // post-talking-heads mix (on normalized probs)
    f32x2 pol[8], poh[8];
    #pragma unroll
    for (int o = 0; o < 8; ++o) { pol[o] = (f32x2){0.f, 0.f}; poh[o] = (f32x2){0.f, 0.f}; }
    #pragma unroll
    for (int i = 0; i < 8; ++i) {
      #pragma unroll
      for (int o = 0; o < 8; ++o) {
        float cth = post_th[o * 8 + i];
        pol[o] += cth * ppl[i]; poh[o] += cth * pph[i];
      }
    }
    // PV: mixed P is already in the 16x16x16 A-fragment layout
    #pragma unroll
    for (int o = 0; o < 8; ++o) {
      bf16x4 pa = {(short)f2bf(pol[o].x), (short)f2bf(pol[o].y),
                   (short)f2bf(poh[o].x), (short)f2bf(poh[o].y)};
      #pragma unroll
      for (int dc = 0; dc < 4; ++dc) {
        bf16x4 b = *(const bf16x4*)(vb + (o * 64 + dc * 16 + li) * 16 + g * 4);
        O[o][dc] = mfma16(pa, b, O[o][dc]);
      }
    }
    if (tt + 1 < NT_) {
      #pragma unroll
      for (int rr = 0; rr < 4; ++rr) {
        int row = w * 4 + rr;
        *(bf16x8*)&Kt[(tt + 1) & 1][row * 512 + (lane ^ (row & 7)) * 8] = kreg[rr];
        int e = (w * 4 + rr) * 32 + (lane >> 1);
        *(bf16x8*)&Vt[(tt + 1) & 1][e * 16 + (lane & 1) * 8] = vreg[rr];
      }
    }
  }
  #pragma unroll
  for (int o = 0; o < 8; ++o)
    #pragma unroll
    for (int dc = 0; dc < 4; ++dc)
      #pragma unroll
      for (int r = 0; r < 4; ++r)
        Oh[(size_t)(n * S_ + q0 + w * 16 + g * 4 + r) * 512 + o * 64 + dc * 16 + li] = O[o][dc][r];
}

// ---------------- output projection: out = Oh @ Wo^T + bo (f32, unchanged this round) ----------------
__global__ __launch_bounds__(256) void out_proj_kernel(
    const float* __restrict__ Oh, const float* __restrict__ Wo,
    const float* __restrict__ bo, float* __restrict__ out) {
  __shared__ float As[64][33];
  __shared__ float Bs[64][33];
  const int t = threadIdx.x;
  const int tx = t & 15, ty = t >> 4;
  const int r0 = blockIdx.y * 64;
  const int c0 = blockIdx.x * 64;
  float acc[4][4] = {};
  for (int k0 = 0; k0 < 512; k0 += 32) {
    __syncthreads();
    for (int idx = t; idx < 2048; idx += 256) {
      int row = idx >> 5, col = idx & 31;
      As[row][col] = Oh[(size_t)(r0 + row) * 512 + k0 + col];
      Bs[row][col] = Wo[(size_t)(c0 + row) * 512 + k0 + col];
    }
    __syncthreads();
    for (int kk = 0; kk < 32; ++kk) {
      float a[4], b[4];
      #pragma unroll
      for (int i = 0; i < 4; ++i) a[i] = As[ty * 4 + i][kk];
      #pragma unroll
      for (int j = 0; j < 4; ++j) b[j] = Bs[tx * 4 + j][kk];
      #pragma unroll
      for (int i = 0; i < 4; ++i)
        #pragma unroll
        for (int j = 0; j < 4; ++j) acc[i][j] += a[i] * b[j];
    }
  }
  #pragma unroll
  for (int i = 0; i < 4; ++i) {
    float4 v4 = make_float4(acc[i][0] + bo[c0 + tx * 4 + 0], acc[i][1] + bo[c0 + tx * 4 + 1],
                            acc[i][2] + bo[c0 + tx * 4 + 2], acc[i][3] + bo[c0 + tx * 4 + 3]);
    *(float4*)&out[(size_t)(r0 + ty * 4 + i) * 512 + c0 + tx * 4] = v4;
  }
}

extern "C" void kernel_launch(void* const* d_in, const int* in_sizes, int n_in,
                              void* d_out, int out_size, void* d_ws, size_t ws_size,
                              hipStream_t stream) {
  const float* values  = (const float*)d_in[0];
  const float* keys    = (const float*)d_in[1];
  const float* queries = (const float*)d_in[2];
  const int*   mask    = (const int*)d_in[3];
  const float* Wv      = (const float*)d_in[4];
  const float* Wk      = (const float*)d_in[5];
  const float* Wq      = (const float*)d_in[6];
  const float* Wo      = (const float*)d_in[7];
  const float* bo      = (const float*)d_in[8];
  const float* pre_th  = (const float*)d_in[9];
  const float* post_th = (const float*)d_in[10];
  const float* pk      = (const float*)d_in[11];
  const float* pv      = (const float*)d_in[12];

  char* ws = (char*)d_ws;
  u16*  Qp = (u16*)ws;                                   // 16384*512*2   = 16,777,216
  u16*  Kp = (u16*)(ws + 16777216);                      // 8*2064*512*2  = 16,908,288
  u16*  VT = (u16*)(ws + 16777216 + 16908288);           // 8*512*2064*2  = 16,908,288
  float* Oh = (float*)(ws + 16777216 + 2 * 16908288);    // 16384*512*4   = 33,554,432
  u32*  bm  = (u32*)(ws + 16777216 + 2 * 16908288 + 33554432);  // 8*64*2048*4 = 4,194,304

  hipLaunchKernelGGL(maskpack_kernel, dim3(4096), dim3(256), 0, stream, mask, bm);
  hipLaunchKernelGGL(proj_kernel, dim3(256, 3), dim3(256), 0, stream,
                     values, keys, queries, Wv, Wk, Wq, Kp, Qp, VT);
  hipLaunchKernelGGL(persist_kernel, dim3(512), dim3(256), 0, stream, pk, pv, Kp, VT);
  hipLaunchKernelGGL(attn_kernel, dim3(32, 8), dim3(256), 0, stream,
                     Qp, Kp, VT, bm, pre_th, post_th, Oh);
  hipLaunchKernelGGL(out_proj_kernel, dim3(8, 256), dim3(256), 0, stream,
                     Oh, Wo, bo, (float*)d_out);
}

// Round 4
// 946.489 us; speedup vs baseline: 95.1069x; 1.0303x over previous
//
#include <hip/hip_runtime.h>

#define N_ 8
#define S_ 2048
#define E_ 512
#define KL_ 2064          // S + P
#define NTT_ 65           // k-tiles of 32 (last covers 2048..2079, valid to 2063)
#define SCALE2 0.063758723f   // (1/sqrt(512)) * log2(e)
#define NEGBIG -700.0f

typedef unsigned short u16;
typedef unsigned int u32;
typedef __attribute__((ext_vector_type(2))) float f32x2;
typedef __attribute__((ext_vector_type(4))) float f32x4;
typedef __attribute__((ext_vector_type(4))) short bf16x4;
typedef __attribute__((ext_vector_type(8))) short bf16x8;

__device__ __forceinline__ u16 f2bf(float x) {
  u32 u = __float_as_uint(x);
  u32 r = (u + 0x7FFFu + ((u >> 16) & 1u)) >> 16;
  return (u16)r;
}

__device__ __forceinline__ float exp2_fast(float x) {
  float r;
  asm("v_exp_f32 %0, %1" : "=v"(r) : "v"(x));
  return r;
}

__device__ __forceinline__ f32x4 mfma16(bf16x4 a, bf16x4 b, f32x4 c) {
#if __has_builtin(__builtin_amdgcn_mfma_f32_16x16x16bf16_1k)
  return __builtin_amdgcn_mfma_f32_16x16x16bf16_1k(a, b, c, 0, 0, 0);
#else
  f32x4 d;
  asm("v_mfma_f32_16x16x16_bf16 %0, %1, %2, %3" : "=v"(d) : "v"(a), "v"(b), "v"(c));
  return d;
#endif
}

__device__ __forceinline__ void gload_lds16(const void* g, void* l) {
  __builtin_amdgcn_global_load_lds((const __attribute__((address_space(1))) unsigned int*)g,
                                   (__attribute__((address_space(3))) unsigned int*)l, 16, 0, 0);
}

// ---------------- mask pack: 1 bit per (q,l), layout bm[n][lword=64][q=2048] ----------------
__global__ __launch_bounds__(256) void maskpack_kernel(const int* __restrict__ mask,
                                                       u32* __restrict__ bm) {
  const int t = threadIdx.x;
  const int w = t >> 6, lane = t & 63;
  const int blk = blockIdx.x;
  const int n = blk >> 9;
  const int qrow = ((blk & 511) << 2) + w;
  const int* row = mask + ((size_t)n * S_ + qrow) * S_;
  __shared__ u32 tl[4][64];
  u32 myword = 0;
  #pragma unroll 4
  for (int k = 0; k < 32; ++k) {
    int v = row[k * 64 + lane];
    unsigned long long b = __ballot(v != 0);
    if ((lane >> 1) == k) myword = (lane & 1) ? (u32)(b >> 32) : (u32)b;
  }
  tl[w][lane] = myword;
  __syncthreads();
  const int qq = t & 3, wi = t >> 2;
  const int qb = ((blk & 511) << 2) + qq;
  bm[((size_t)n * 64 + wi) * S_ + qb] = tl[qq][wi];
}

// ---------------- projections (MFMA): Qp/Kp bf16 natural, V transposed VT[n][e][l] ----------------
__global__ __launch_bounds__(256, 2) void proj_kernel(
    const float* __restrict__ V_, const float* __restrict__ K_, const float* __restrict__ Q_,
    const float* __restrict__ Wv, const float* __restrict__ Wk, const float* __restrict__ Wq,
    u16* __restrict__ Kp, u16* __restrict__ Qp, u16* __restrict__ VT) {
  __shared__ u16 xt[64 * 512];
  __shared__ u16 wt[64 * 64];
  const int tz = blockIdx.y;
  const float* X = (tz == 0) ? V_ : (tz == 1) ? K_ : Q_;
  const float* W = (tz == 0) ? Wv : (tz == 1) ? Wk : Wq;
  const int t = threadIdx.x, lane = t & 63, w = t >> 6, g = lane >> 4, li = lane & 15;
  const int rb = blockIdx.x * 64;
  const int nn = rb >> 11, sb = rb & 2047;

  for (int c = t; c < 512; c += 256) {
    int r = c >> 3, s = c & 7;
    float4 a = *(const float4*)&W[r * 64 + s * 8];
    float4 b = *(const float4*)&W[r * 64 + s * 8 + 4];
    bf16x8 v = {(short)f2bf(a.x), (short)f2bf(a.y), (short)f2bf(a.z), (short)f2bf(a.w),
                (short)f2bf(b.x), (short)f2bf(b.y), (short)f2bf(b.z), (short)f2bf(b.w)};
    *(bf16x8*)&wt[r * 64 + ((s ^ (r & 7)) * 8)] = v;
  }
  for (int c = t; c < 4096; c += 256) {
    int r = c >> 6, s = c & 63;
    const float* src = &X[(size_t)(rb + r) * 512 + s * 8];
    float4 a = *(const float4*)src;
    float4 b = *(const float4*)(src + 4);
    bf16x8 v = {(short)f2bf(a.x), (short)f2bf(a.y), (short)f2bf(a.z), (short)f2bf(a.w),
                (short)f2bf(b.x), (short)f2bf(b.y), (short)f2bf(b.z), (short)f2bf(b.w)};
    *(bf16x8*)&xt[r * 512 + ((s ^ (r & 7)) * 8)] = v;
  }
  __syncthreads();

  bf16x8 fx[8][2];
  #pragma unroll
  for (int h = 0; h < 8; ++h)
    #pragma unroll
    for (int dh = 0; dh < 2; ++dh) {
      int row = w * 16 + li;
      fx[h][dh] = *(const bf16x8*)&xt[row * 512 + (((h * 8 + dh * 4 + g) ^ (row & 7)) * 8)];
    }
  bf16x8 fw[4][2];
  #pragma unroll
  for (int c = 0; c < 4; ++c)
    #pragma unroll
    for (int dh = 0; dh < 2; ++dh) {
      int row = c * 16 + li;
      fw[c][dh] = *(const bf16x8*)&wt[row * 64 + (((dh * 4 + g) ^ (row & 7)) * 8)];
    }

  f32x4 C[8][4];
  #pragma unroll
  for (int h = 0; h < 8; ++h)
    #pragma unroll
    for (int c = 0; c < 4; ++c) C[h][c] = (f32x4){0.f, 0.f, 0.f, 0.f};

  if (tz == 0) {
    #pragma unroll
    for (int h = 0; h < 8; ++h)
      #pragma unroll
      for (int dh = 0; dh < 2; ++dh)
        #pragma unroll
        for (int c = 0; c < 4; ++c)
          C[h][c] = __builtin_amdgcn_mfma_f32_16x16x32_bf16(fw[c][dh], fx[h][dh], C[h][c], 0, 0, 0);
    #pragma unroll
    for (int h = 0; h < 8; ++h)
      #pragma unroll
      for (int c = 0; c < 4; ++c)
        #pragma unroll
        for (int r = 0; r < 4; ++r) {
          int e = h * 64 + c * 16 + g * 4 + r;
          VT[((size_t)(nn * 512 + e)) * KL_ + sb + w * 16 + li] = f2bf(C[h][c][r]);
        }
  } else {
    #pragma unroll
    for (int h = 0; h < 8; ++h)
      #pragma unroll
      for (int dh = 0; dh < 2; ++dh)
        #pragma unroll
        for (int c = 0; c < 4; ++c)
          C[h][c] = __builtin_amdgcn_mfma_f32_16x16x32_bf16(fx[h][dh], fw[c][dh], C[h][c], 0, 0, 0);
    #pragma unroll
    for (int h = 0; h < 8; ++h)
      #pragma unroll
      for (int c = 0; c < 4; ++c)
        #pragma unroll
        for (int r = 0; r < 4; ++r) {
          int e = h * 64 + c * 16 + li;
          u16 val = f2bf(C[h][c][r]);
          if (tz == 2) Qp[(size_t)(rb + w * 16 + g * 4 + r) * 512 + e] = val;
          else Kp[((size_t)nn * KL_ + sb + w * 16 + g * 4 + r) * 512 + e] = val;
        }
  }
}

// ---------------- persistent tokens ----------------
__global__ __launch_bounds__(256) void persist_kernel(const float* __restrict__ pk,
                                                      const float* __restrict__ pv,
                                                      u16* __restrict__ Kp, u16* __restrict__ VT) {
  int id = blockIdx.x * 256 + threadIdx.x;
  int tensor = id >> 16, rem = id & 65535;
  int n = rem >> 13, p = (rem >> 9) & 15, e = rem & 511;
  if (tensor == 0) Kp[((size_t)n * KL_ + S_ + p) * 512 + e] = f2bf(pk[p * 512 + e]);
  else VT[((size_t)(n * 512 + e)) * KL_ + S_ + p] = f2bf(pv[p * 512 + e]);
}

// ---------------- fused attention: 8 waves (4 q-strips x 2 l-halves), TK=32, async staged ----------------
__global__ __launch_bounds__(512, 2) void attn_kernel(
    const u16* __restrict__ Qp, const u16* __restrict__ Kp, const u16* __restrict__ VT,
    const u32* __restrict__ bm, const float* __restrict__ pre_th,
    const float* __restrict__ post_th, u16* __restrict__ Ohb) {
  __shared__ __align__(16) char smem[151552];          // 148 KB
  u16* KtB = (u16*)smem;                               // 2 x [32][512]  (64 KB)
  u16* VtB = (u16*)(smem + 65536);                     // 2 x [512][32]  (64 KB)
  u32* mlds = (u32*)(smem + 131072);                   // [64][64]       (16 KB)
  float* Zbuf = (float*)(smem + 147456);               // [2][64][8]     (4 KB)

  const int t = threadIdx.x, lane = t & 63, w = t >> 6, g = lane >> 4, li = lane & 15;
  const int qw = w & 3, lh = w >> 2;
  const int n = blockIdx.y, q0 = blockIdx.x * 64;
  const int myq = q0 + qw * 16 + li;
  const float myq_f = (float)myq;

  const u16* Kbase = Kp + (size_t)n * KL_ * 512;
  const u16* Vbase = VT + (size_t)n * 512 * KL_;

  // ---- staging helpers (async, pre-swizzled global source, linear LDS dest) ----
  #define STAGE_K(buf, tile) {                                                          \
    _Pragma("unroll")                                                                   \
    for (int i_ = 0; i_ < 4; ++i_) {                                                    \
      int row_ = w + i_ * 8;                                                            \
      gload_lds16(Kbase + (size_t)((tile) * 32 + row_) * 512 + ((lane ^ (row_ & 7)) * 8),\
                  KtB + (buf) * 16384 + row_ * 512);                                    \
    } }
  #define STAGE_V(buf, tile) {                                                          \
    _Pragma("unroll")                                                                   \
    for (int i_ = 0; i_ < 4; ++i_) {                                                    \
      int c_ = t + i_ * 512;                                                            \
      int e_ = c_ >> 2, q16_ = c_ & 3;                                                  \
      gload_lds16(Vbase + (size_t)e_ * KL_ + (tile) * 32 + ((q16_ ^ (e_ & 3)) * 8),     \
                  VtB + (buf) * 16384 + (i_ * 512 + w * 64) * 8);                       \
    } }

  // mask words
  for (int idx = t; idx < 4096; idx += 512)
    mlds[idx] = bm[((size_t)n * 64 + (idx >> 6)) * S_ + q0 + (idx & 63)];

  // Q fragments (regs, whole kernel)
  bf16x8 qf[8][2];
  {
    const u16* qrow = Qp + (size_t)(n * S_ + myq) * 512;
    #pragma unroll
    for (int h = 0; h < 8; ++h)
      #pragma unroll
      for (int dh = 0; dh < 2; ++dh)
        qf[h][dh] = *(const bf16x8*)(qrow + h * 64 + dh * 32 + g * 8);
  }
  // negated mixed ALiBi slopes (base-2 scaled)
  float nms[8];
  #pragma unroll
  for (int i = 0; i < 8; ++i) {
    float a = 0.f;
    #pragma unroll
    for (int j = 0; j < 8; ++j) a += pre_th[i * 8 + j] * exp2f(-(float)(j + 1));
    nms[i] = -a * SCALE2;
  }

  float Zr[8];
  #pragma unroll
  for (int i = 0; i < 8; ++i) Zr[i] = 0.f;

  STAGE_K(0, 0)
  __syncthreads();

  // ================= PASS 1: Z per (q, raw head) — no max tracking (shift -64) =================
  for (int tt = 0; tt < NTT_; ++tt) {
    if (tt + 1 < NTT_) STAGE_K((tt + 1) & 1, tt + 1)
    const u16* kb = KtB + (tt & 1) * 16384;
    f32x4 C[8];
    #pragma unroll
    for (int h = 0; h < 8; ++h) C[h] = (f32x4){0.f, 0.f, 0.f, 0.f};
    #pragma unroll
    for (int h = 0; h < 8; ++h)
      #pragma unroll
      for (int dh = 0; dh < 2; ++dh) {
        bf16x8 a = *(const bf16x8*)(kb + (lh * 16 + li) * 512 + (((h * 8 + dh * 4 + g) ^ (li & 7)) * 8));
        C[h] = __builtin_amdgcn_mfma_f32_16x16x32_bf16(a, qf[h][dh], C[h], 0, 0, 0);
      }
    u32 mbits;
    float dist[4];
    const int l0 = tt * 32 + lh * 16 + g * 4;
    if (tt < 64) {
      mbits = (mlds[tt * 64 + qw * 16 + li] >> (lh * 16 + g * 4)) & 0xFu;
      #pragma unroll
      for (int r = 0; r < 4; ++r) dist[r] = fabsf(myq_f - (float)(l0 + r));
    } else {
      mbits = (lh == 0) ? 0xFu : 0u;
      #pragma unroll
      for (int r = 0; r < 4; ++r) dist[r] = 0.f;
    }
    f32x2 accl[8], acch[8];
    #pragma unroll
    for (int i = 0; i < 8; ++i) { accl[i] = (f32x2){0.f, 0.f}; acch[i] = (f32x2){0.f, 0.f}; }
    #pragma unroll
    for (int j = 0; j < 8; ++j) {
      f32x2 elo = {C[j].x, C[j].y}, ehi = {C[j].z, C[j].w};
      #pragma unroll
      for (int i = 0; i < 8; ++i) {
        float p = pre_th[i * 8 + j];
        accl[i] += p * elo; acch[i] += p * ehi;
      }
    }
    const bool al = (tt < 64);
    #pragma unroll
    for (int i = 0; i < 8; ++i) {
      float t0 = fmaf(accl[i].x, SCALE2, -64.f);
      float t1 = fmaf(accl[i].y, SCALE2, -64.f);
      float t2 = fmaf(acch[i].x, SCALE2, -64.f);
      float t3 = fmaf(acch[i].y, SCALE2, -64.f);
      if (al) {
        t0 = fmaf(dist[0], nms[i], t0); t1 = fmaf(dist[1], nms[i], t1);
        t2 = fmaf(dist[2], nms[i], t2); t3 = fmaf(dist[3], nms[i], t3);
      }
      t0 = (mbits & 1u) ? t0 : NEGBIG; t1 = (mbits & 2u) ? t1 : NEGBIG;
      t2 = (mbits & 4u) ? t2 : NEGBIG; t3 = (mbits & 8u) ? t3 : NEGBIG;
      Zr[i] += (exp2_fast(t0) + exp2_fast(t1)) + (exp2_fast(t2) + exp2_fast(t3));
    }
    __syncthreads();
  }

  // prefetch pass-2 tile 0 (drained by the Zbuf barrier)
  STAGE_K(0, 0)
  STAGE_V(0, 0)

  // combine Z: across g (shfl), across l-halves (LDS)
  #pragma unroll
  for (int i = 0; i < 8; ++i) {
    Zr[i] += __shfl_xor(Zr[i], 16);
    Zr[i] += __shfl_xor(Zr[i], 32);
  }
  if (lane < 16) {
    #pragma unroll
    for (int i = 0; i < 8; ++i) Zbuf[(lh * 64 + qw * 16 + li) * 8 + i] = Zr[i];
  }
  __syncthreads();
  float nm1[8];
  #pragma unroll
  for (int i = 0; i < 8; ++i) {
    float zt = Zbuf[(qw * 16 + li) * 8 + i] + Zbuf[(64 + qw * 16 + li) * 8 + i];
    nm1[i] = -(64.f + __log2f(zt));
  }

  // ================= PASS 2: normalize, post-mix, PV =================
  f32x4 O[8][4];
  #pragma unroll
  for (int o = 0; o < 8; ++o)
    #pragma unroll
    for (int dc = 0; dc < 4; ++dc) O[o][dc] = (f32x4){0.f, 0.f, 0.f, 0.f};

  const int cloff = (((lh * 2 + (g >> 1)) ^ (li & 3)) * 8) + (g & 1) * 4;  // u16 units

  for (int tt = 0; tt < NTT_; ++tt) {
    if (tt + 1 < NTT_) { STAGE_K((tt + 1) & 1, tt + 1) STAGE_V((tt + 1) & 1, tt + 1) }
    const u16* kb = KtB + (tt & 1) * 16384;
    const u16* vb = VtB + (tt & 1) * 16384;
    f32x4 C[8];
    #pragma unroll
    for (int h = 0; h < 8; ++h) C[h] = (f32x4){0.f, 0.f, 0.f, 0.f};
    #pragma unroll
    for (int h = 0; h < 8; ++h)
      #pragma unroll
      for (int dh = 0; dh < 2; ++dh) {
        bf16x8 a = *(const bf16x8*)(kb + (lh * 16 + li) * 512 + (((h * 8 + dh * 4 + g) ^ (li & 7)) * 8));
        C[h] = __builtin_amdgcn_mfma_f32_16x16x32_bf16(a, qf[h][dh], C[h], 0, 0, 0);
      }
    u32 mbits;
    float dist[4];
    const int l0 = tt * 32 + lh * 16 + g * 4;
    if (tt < 64) {
      mbits = (mlds[tt * 64 + qw * 16 + li] >> (lh * 16 + g * 4)) & 0xFu;
      #pragma unroll
      for (int r = 0; r < 4; ++r) dist[r] = fabsf(myq_f - (float)(l0 + r));
    } else {
      mbits = (lh == 0) ? 0xFu : 0u;
      #pragma unroll
      for (int r = 0; r < 4; ++r) dist[r] = 0.f;
    }
    f32x2 accl[8], acch[8];
    #pragma unroll
    for (int i = 0; i < 8; ++i) { accl[i] = (f32x2){0.f, 0.f}; acch[i] = (f32x2){0.f, 0.f}; }
    #pragma unroll
    for (int j = 0; j < 8; ++j) {
      f32x2 elo = {C[j].x, C[j].y}, ehi = {C[j].z, C[j].w};
      #pragma unroll
      for (int i = 0; i < 8; ++i) {
        float p = pre_th[i * 8 + j];
        accl[i] += p * elo; acch[i] += p * ehi;
      }
    }
    const bool al = (tt < 64);
    f32x2 ppl[8], pph[8];
    #pragma unroll
    for (int i = 0; i < 8; ++i) {
      float t0 = fmaf(accl[i].x, SCALE2, nm1[i]);
      float t1 = fmaf(accl[i].y, SCALE2, nm1[i]);
      float t2 = fmaf(acch[i].x, SCALE2, nm1[i]);
      float t3 = fmaf(acch[i].y, SCALE2, nm1[i]);
      if (al) {
        t0 = fmaf(dist[0], nms[i], t0); t1 = fmaf(dist[1], nms[i], t1);
        t2 = fmaf(dist[2], nms[i], t2); t3 = fmaf(dist[3], nms[i], t3);
      }
      t0 = (mbits & 1u) ? t0 : NEGBIG; t1 = (mbits & 2u) ? t1 : NEGBIG;
      t2 = (mbits & 4u) ? t2 : NEGBIG; t3 = (mbits & 8u) ? t3 : NEGBIG;
      ppl[i] = (f32x2){exp2_fast(t0), exp2_fast(t1)};
      pph[i] = (f32x2){exp2_fast(t2), exp2_fast(t3)};
    }
    f32x2 pol[8], poh[8];
    #pragma unroll
    for (int o = 0; o < 8; ++o) { pol[o] = (f32x2){0.f, 0.f}; poh[o] = (f32x2){0.f, 0.f}; }
    #pragma unroll
    for (int i = 0; i < 8; ++i) {
      #pragma unroll
      for (int o = 0; o < 8; ++o) {
        float c = post_th[o * 8 + i];
        pol[o] += c * ppl[i]; poh[o] += c * pph[i];
      }
    }
    #pragma unroll
    for (int o = 0; o < 8; ++o) {
      bf16x4 pa = {(short)f2bf(pol[o].x), (short)f2bf(pol[o].y),
                   (short)f2bf(poh[o].x), (short)f2bf(poh[o].y)};
      #pragma unroll
      for (int dc = 0; dc < 4; ++dc) {
        int e = o * 64 + dc * 16 + li;
        bf16x4 b = *(const bf16x4*)(vb + e * 32 + cloff);
        O[o][dc] = mfma16(pa, b, O[o][dc]);
      }
    }
    __syncthreads();
  }

  // ---- epilogue: combine l-halves via LDS, store bf16 ----
  float* ep = (float*)smem;   // 128 KB overlay on Kt+Vt
  if (lh == 1) {
    #pragma unroll
    for (int o = 0; o < 8; ++o)
      #pragma unroll
      for (int dc = 0; dc < 4; ++dc)
        *(f32x4*)&ep[qw * 8192 + ((o * 4 + dc) * 64 + li * 4 + g) * 4] = O[o][dc];
  }
  __syncthreads();
  if (lh == 0) {
    u16* dst = Ohb + (size_t)(n * S_ + q0 + qw * 16) * 512;
    #pragma unroll
    for (int o = 0; o < 8; ++o)
      #pragma unroll
      for (int dc = 0; dc < 4; ++dc) {
        f32x4 oth = *(const f32x4*)&ep[qw * 8192 + ((o * 4 + dc) * 64 + li * 4 + g) * 4];
        f32x4 v = O[o][dc] + oth;
        int e = o * 64 + dc * 16 + li;
        #pragma unroll
        for (int r = 0; r < 4; ++r) dst[(size_t)(g * 4 + r) * 512 + e] = f2bf(v[r]);
      }
  }
  #undef STAGE_K
  #undef STAGE_V
}

// ---------------- output projection (bf16 MFMA): out = Ohb @ Wo^T + bo ----------------
__global__ __launch_bounds__(256) void out_proj_kernel(
    const u16* __restrict__ Ohb, const float* __restrict__ Wo,
    const float* __restrict__ bo, float* __restrict__ out) {
  __shared__ __align__(16) u16 As[2][128 * 32];
  __shared__ __align__(16) u16 Bs[2][128 * 32];
  const int t = threadIdx.x, lane = t & 63, w = t >> 6, g = lane >> 4, li = lane & 15;
  const int wq = w & 1, wp = w >> 1;
  const int r0 = blockIdx.y * 128, c0 = blockIdx.x * 128;

  #define STAGE_A(buf, ks) {                                                  \
    _Pragma("unroll")                                                         \
    for (int i_ = 0; i_ < 2; ++i_) {                                          \
      int c_ = t + i_ * 256;                                                  \
      gload_lds16(Ohb + (size_t)(r0 + (c_ >> 2)) * 512 + (ks) + (c_ & 3) * 8, \
                  &As[buf][(i_ * 256 + w * 64) * 8]);                         \
    } }
  #define STAGE_B(buf, ks) {                                                  \
    _Pragma("unroll")                                                         \
    for (int i_ = 0; i_ < 2; ++i_) {                                          \
      int c_ = t + i_ * 256;                                                  \
      const float* s_ = &Wo[(size_t)(c0 + (c_ >> 2)) * 512 + (ks) + (c_ & 3) * 8]; \
      float4 a_ = *(const float4*)s_;                                         \
      float4 b_ = *(const float4*)(s_ + 4);                                   \
      bf16x8 v_ = {(short)f2bf(a_.x), (short)f2bf(a_.y), (short)f2bf(a_.z), (short)f2bf(a_.w), \
                   (short)f2bf(b_.x), (short)f2bf(b_.y), (short)f2bf(b_.z), (short)f2bf(b_.w)}; \
      *(bf16x8*)&Bs[buf][c_ * 8] = v_;                                        \
    } }

  f32x4 acc[4][4];
  #pragma unroll
  for (int m = 0; m < 4; ++m)
    #pragma unroll
    for (int nn = 0; nn < 4; ++nn) acc[m][nn] = (f32x4){0.f, 0.f, 0.f, 0.f};

  STAGE_A(0, 0)
  STAGE_B(0, 0)
  __syncthreads();
  for (int s = 0; s < 16; ++s) {
    if (s + 1 < 16) { STAGE_A((s + 1) & 1, (s + 1) * 32) STAGE_B((s + 1) & 1, (s + 1) * 32) }
    const u16* ab = As[s & 1];
    const u16* bb = Bs[s & 1];
    bf16x8 af[4], bf[4];
    #pragma unroll
    for (int m = 0; m < 4; ++m) af[m] = *(const bf16x8*)(ab + (wp * 64 + m * 16 + li) * 32 + g * 8);
    #pragma unroll
    for (int nn = 0; nn < 4; ++nn) bf[nn] = *(const bf16x8*)(bb + (wq * 64 + nn * 16 + li) * 32 + g * 8);
    #pragma unroll
    for (int m = 0; m < 4; ++m)
      #pragma unroll
      for (int nn = 0; nn < 4; ++nn)
        acc[m][nn] = __builtin_amdgcn_mfma_f32_16x16x32_bf16(af[m], bf[nn], acc[m][nn], 0, 0, 0);
    __syncthreads();
  }
  #pragma unroll
  for (int nn = 0; nn < 4; ++nn) {
    int col = c0 + wq * 64 + nn * 16 + li;
    float bv = bo[col];
    #pragma unroll
    for (int m = 0; m < 4; ++m)
      #pragma unroll
      for (int r = 0; r < 4; ++r)
        out[(size_t)(r0 + wp * 64 + m * 16 + g * 4 + r) * 512 + col] = acc[m][nn][r] + bv;
  }
  #undef STAGE_A
  #undef STAGE_B
}

extern "C" void kernel_launch(void* const* d_in, const int* in_sizes, int n_in,
                              void* d_out, int out_size, void* d_ws, size_t ws_size,
                              hipStream_t stream) {
  const float* values  = (const float*)d_in[0];
  const float* keys    = (const float*)d_in[1];
  const float* queries = (const float*)d_in[2];
  const int*   mask    = (const int*)d_in[3];
  const float* Wv      = (const float*)d_in[4];
  const float* Wk      = (const float*)d_in[5];
  const float* Wq      = (const float*)d_in[6];
  const float* Wo      = (const float*)d_in[7];
  const float* bo      = (const float*)d_in[8];
  const float* pre_th  = (const float*)d_in[9];
  const float* post_th = (const float*)d_in[10];
  const float* pk      = (const float*)d_in[11];
  const float* pv      = (const float*)d_in[12];

  char* ws = (char*)d_ws;
  u16*  Qp  = (u16*)ws;                          // 16,777,216
  u16*  Kp  = (u16*)(ws + 16777216);             // 16,908,288
  u16*  VT  = (u16*)(ws + 33685504);             // 16,908,288
  u16*  Ohb = (u16*)(ws + 50593792);             // 16,777,216
  u32*  bm  = (u32*)(ws + 67371008);             // 4,194,304

  hipLaunchKernelGGL(maskpack_kernel, dim3(4096), dim3(256), 0, stream, mask, bm);
  hipLaunchKernelGGL(proj_kernel, dim3(256, 3), dim3(256), 0, stream,
                     values, keys, queries, Wv, Wk, Wq, Kp, Qp, VT);
  hipLaunchKernelGGL(persist_kernel, dim3(512), dim3(256), 0, stream, pk, pv, Kp, VT);
  hipLaunchKernelGGL(attn_kernel, dim3(32, 8), dim3(512), 0, stream,
                     Qp, Kp, VT, bm, pre_th, post_th, Ohb);
  hipLaunchKernelGGL(out_proj_kernel, dim3(4, 128), dim3(256), 0, stream,
                     Ohb, Wo, bo, (float*)d_out);
}